// Round 7
// baseline (243.406 us; speedup 1.0000x reference)
//
#include <hip/hip_runtime.h>
#include <hip/hip_bf16.h>

// Problem: B=512, N_SLOTS=128, IN=2048, MEM=64, OUT=2048.
// Runtime dtype detection (flag in ws): detector inspects bit patterns of x;
// compute kernels templated on <BF16>, both variants launched, mismatch exits.
// Evidence (R4-R6): world is fp32 buffers holding bf16-quantized values.
// d_out = [output (512*2048) | new_memory (512*128*64)], input dtype.

#define NB    512
#define NSLOT 128
#define DIN   2048
#define DMEM  64
#define DOUT  2048
#define PXW   130   // x-projection width: 64 (q) + 1 (forget) + 65 (remember)
#define KTOT  (DIN + 2 * DMEM)   // 2176

typedef __hip_bfloat16 bf16;
typedef __attribute__((ext_vector_type(8))) short short8;
typedef __attribute__((ext_vector_type(4))) float f32x4;

template<bool BF16>
__device__ __forceinline__ float ld(const void* p, size_t i) {
  if (BF16) return __bfloat162float(((const bf16*)p)[i]);
  return ((const float*)p)[i];
}
template<bool BF16>
__device__ __forceinline__ void st(void* p, size_t i, float v) {
  if (BF16) ((bf16*)p)[i] = __float2bfloat16(v);
  else      ((float*)p)[i] = v;
}

// f32 -> bf16 bits, round-to-nearest-even (inputs are finite/sane).
__device__ __forceinline__ unsigned short f2bu(float f) {
  unsigned int u = __builtin_bit_cast(unsigned int, f);
  u = (u + 0x7FFFu + ((u >> 16) & 1u)) >> 16;
  return (unsigned short)u;
}
// bf16 bits -> f32 (exact)
__device__ __forceinline__ float bu2f(unsigned short u) {
  unsigned int w = ((unsigned int)u) << 16;
  return __builtin_bit_cast(float, w);
}

// ---------------------------------------------------------------------------
// Detector: even uint16 positions of x. bf16 data -> sane exponents (~100%);
// f32 data -> even positions are mantissa low-halves (~16% sane). flag=1=bf16.
// ---------------------------------------------------------------------------
__global__ void k_detect(const void* __restrict__ x, int* __restrict__ flag) {
  __shared__ int cnt;
  if (threadIdx.x == 0) cnt = 0;
  __syncthreads();
  const unsigned short* u = (const unsigned short*)x;
  int sane = 0;
  for (int i = 0; i < 8; ++i) {
    unsigned short v = u[(threadIdx.x * 8 + i) * 2];
    int e = (v >> 7) & 0xFF;
    if (e >= 100 && e <= 140) sane++;
  }
  atomicAdd(&cnt, sane);
  __syncthreads();
  if (threadIdx.x == 0) *flag = (cnt > 1024) ? 1 : 0;
}

// ---------------------------------------------------------------------------
// Kernel 1a: pack x-side projection weights transposed into Wt[130][2048]
// (bf16 bits). Column j: j<64 -> W_ar[:,j]; j==64 -> W_f[:2048]; j>=65 ->
// W_r[:2048, j-65]. LDS tile transpose, 32 blocks each covering 64 k's.
// ---------------------------------------------------------------------------
template<bool BF16>
__global__ __launch_bounds__(256) void k_packW(
    const int* __restrict__ flag,
    const void* __restrict__ W_ar, const void* __restrict__ W_f,
    const void* __restrict__ W_r,
    unsigned short* __restrict__ Wt) {
  if ((*flag != 0) != BF16) return;
  __shared__ float tile[PXW * 65];
  int k0 = blockIdx.x * 64;
  for (int i = threadIdx.x; i < 64 * PXW; i += 256) {
    int kl = i / PXW, j = i - kl * PXW;
    int k = k0 + kl;
    float v;
    if (j < 64)       v = ld<BF16>(W_ar, (size_t)k * 64 + j);
    else if (j == 64) v = ld<BF16>(W_f, k);
    else              v = ld<BF16>(W_r, (size_t)k * 65 + (j - 65));
    tile[j * 65 + kl] = v;
  }
  __syncthreads();
  for (int i = threadIdx.x; i < PXW * 64; i += 256) {
    int j = i >> 6, kk = i & 63;
    Wt[(size_t)j * DIN + k0 + kk] = f2bu(tile[j * 65 + kk]);
  }
}

// ---------------------------------------------------------------------------
// Kernel 1b: px[b][j] = dot(x[b], Wt[j]) + bias[j].
// ---------------------------------------------------------------------------
union U8x16 { uint4 v; unsigned short u[8]; };

template<bool BF16>
__global__ __launch_bounds__(256) void k_proj_dot(
    const int* __restrict__ flag,
    const void* __restrict__ x,
    const unsigned short* __restrict__ Wt,
    const void* __restrict__ b_ar, const void* __restrict__ b_f,
    const void* __restrict__ b_r,
    float* __restrict__ px) {
  if ((*flag != 0) != BF16) return;
  __shared__ float xs[DIN];
  int b = blockIdx.x;
  for (int k = threadIdx.x; k < DIN; k += 256) xs[k] = ld<BF16>(x, (size_t)b * DIN + k);
  __syncthreads();
  int wv = threadIdx.x >> 6, lane = threadIdx.x & 63;
  for (int j = wv; j < PXW; j += 4) {
    const unsigned short* wc = Wt + (size_t)j * DIN;
    float acc = 0.f;
#pragma unroll
    for (int i = 0; i < 4; ++i) {
      int k0 = i * 512 + lane * 8;
      U8x16 t; t.v = *(const uint4*)(wc + k0);
      const float4* xp = (const float4*)&xs[k0];
      float4 xa = xp[0], xb = xp[1];
      acc += xa.x * bu2f(t.u[0]) + xa.y * bu2f(t.u[1])
           + xa.z * bu2f(t.u[2]) + xa.w * bu2f(t.u[3])
           + xb.x * bu2f(t.u[4]) + xb.y * bu2f(t.u[5])
           + xb.z * bu2f(t.u[6]) + xb.w * bu2f(t.u[7]);
    }
#pragma unroll
    for (int off = 32; off; off >>= 1) acc += __shfl_xor(acc, off, 64);
    if (lane == 0) {
      float bias;
      if (j < 64)       bias = ld<BF16>(b_ar, j);
      else if (j == 64) bias = ld<BF16>(b_f, 0);
      else              bias = ld<BF16>(b_r, j - 65);
      px[b * PXW + j] = acc + bias;
    }
  }
}

// ---------------------------------------------------------------------------
// Kernel 2: per-batch fused — per-slot dots, two LDS-tree softmaxes, recalls,
// gated memory update. (Unchanged.)
// ---------------------------------------------------------------------------
template<bool BF16>
__global__ __launch_bounds__(256) void k_fused(
    const int* __restrict__ flag,
    const void* __restrict__ memory,
    const void* __restrict__ W_pr, const void* __restrict__ b_pr,
    const void* __restrict__ W_f,  const void* __restrict__ W_r,
    const float* __restrict__ px,
    float* __restrict__ ap,          // [512][128]: active(64) | passive(64)
    void* __restrict__ dout) {
  if ((*flag != 0) != BF16) return;
  __shared__ float mem_s[NSLOT * 65];
  __shared__ float wrm_s[64 * 68];   // W_r rows 2048..2111, [k][j], j<65
  __shared__ float wfm_s[64], wpr_s[64], qs[64], pxr_s[65];
  __shared__ float sa[128], sp[128], ra[128], rb[128];
  __shared__ float forget_s[128], r64_s[128];

  int b = blockIdx.x, tid = threadIdx.x;
  size_t mb = (size_t)b * (NSLOT * DMEM);
  for (int i = tid; i < NSLOT * DMEM; i += 256)
    mem_s[(i >> 6) * 65 + (i & 63)] = ld<BF16>(memory, mb + i);
  for (int i = tid; i < 64 * 65; i += 256)
    wrm_s[(i / 65) * 68 + (i % 65)] = ld<BF16>(W_r, 2048 * 65 + i);
  if (tid < 64) {
    wfm_s[tid] = ld<BF16>(W_f, 2048 + tid);
    wpr_s[tid] = ld<BF16>(W_pr, tid);
    qs[tid]    = px[b * PXW + tid];
  }
  if (tid < 65) pxr_s[tid] = px[b * PXW + 65 + tid];
  __syncthreads();

  float pxf = px[b * PXW + 64];

  if (tid < 128) {
    const float* mr = &mem_s[tid * 65];
    float aa = 0.f, pp = 0.f, ff = 0.f, rr = 0.f;
#pragma unroll 8
    for (int k = 0; k < 64; ++k) {
      float m = mr[k];
      aa += m * qs[k];
      pp += m * wpr_s[k];
      ff += m * wfm_s[k];
      rr += m * wrm_s[k * 68 + 64];
    }
    sa[tid] = aa;
    sp[tid] = pp + ld<BF16>(b_pr, 0);
    forget_s[tid] = 1.1f / (1.f + __expf(-(ff + pxf)));
    r64_s[tid]    = rr + pxr_s[64];
  }
  __syncthreads();

  if (tid < 128) ra[tid] = sa[tid]; else rb[tid - 128] = sp[tid - 128];
  __syncthreads();
  for (int s = 64; s; s >>= 1) {
    if (tid < s) ra[tid] = fmaxf(ra[tid], ra[tid + s]);
    else if (tid >= 128 && tid < 128 + s) rb[tid - 128] = fmaxf(rb[tid - 128], rb[tid - 128 + s]);
    __syncthreads();
  }
  float mxA = ra[0], mxB = rb[0];
  __syncthreads();
  if (tid < 128) { float e = __expf(sa[tid] - mxA); sa[tid] = e; ra[tid] = e; }
  else           { float e = __expf(sp[tid - 128] - mxB); sp[tid - 128] = e; rb[tid - 128] = e; }
  __syncthreads();
  for (int s = 64; s; s >>= 1) {
    if (tid < s) ra[tid] += ra[tid + s];
    else if (tid >= 128 && tid < 128 + s) rb[tid - 128] += rb[tid - 128 + s];
    __syncthreads();
  }
  float invA = 1.f / ra[0], invB = 1.f / rb[0];
  __syncthreads();
  if (tid < 128) sa[tid] *= invA; else sp[tid - 128] *= invB;
  __syncthreads();

  if (tid < 128) {
    int m = tid & 63;
    const float* w = (tid < 64) ? sa : sp;
    float acc = 0.f;
#pragma unroll 8
    for (int n = 0; n < NSLOT; ++n) acc += mem_s[n * 65 + m] * w[n];
    ap[b * 128 + tid] = acc;
  }

  size_t obase = (size_t)NB * DOUT + mb;
  for (int Q = tid; Q < NSLOT * 16; Q += 256) {
    int n = Q >> 4, j0 = (Q & 15) * 4;
    const float* mr = &mem_s[n * 65];
    float r0 = 0.f, r1 = 0.f, r2 = 0.f, r3 = 0.f;
#pragma unroll 8
    for (int k = 0; k < 64; ++k) {
      float mv = mr[k];
      const float* wr = &wrm_s[k * 68 + j0];
      r0 += mv * wr[0]; r1 += mv * wr[1]; r2 += mv * wr[2]; r3 += mv * wr[3];
    }
    float fg = forget_s[n], r64 = r64_s[n];
    size_t o = obase + n * DMEM + j0;
    st<BF16>(dout, o + 0, mr[j0 + 0] * fg + r64 * (r0 + pxr_s[j0 + 0]));
    st<BF16>(dout, o + 1, mr[j0 + 1] * fg + r64 * (r1 + pxr_s[j0 + 1]));
    st<BF16>(dout, o + 2, mr[j0 + 2] * fg + r64 * (r2 + pxr_s[j0 + 2]));
    st<BF16>(dout, o + 3, mr[j0 + 3] * fg + r64 * (r3 + pxr_s[j0 + 3]));
  }
}

// ---------------------------------------------------------------------------
// Kernel 3: output = [x | active | passive] @ W_o + b_o  via bf16 MFMA.
// 64x64 tile, BK=32, 4 waves in 2x2. v2: double-buffered LDS + register
// prefetch (1 barrier/iter, global latency overlapped with MFMA) and
// rotated B scatter-writes (j=(t+lane&7)&7) -> 2-way (free) instead of 8-way
// bank conflicts.
// ---------------------------------------------------------------------------
#define ASTR 40
#define TSZ  (64 * ASTR)
#define NK   (KTOT / 32)

template<bool BF16>
__global__ __launch_bounds__(256) void k_out_gemm(
    const int* __restrict__ flag,
    const void* __restrict__ x, const float* __restrict__ ap,
    const void* __restrict__ Wo, const void* __restrict__ bo,
    void* __restrict__ dout) {
  if ((*flag != 0) != BF16) return;
  __shared__ unsigned short As[2][TSZ];
  __shared__ unsigned short Bs[2][TSZ];
  int tid = threadIdx.x;
  int col0 = blockIdx.x * 64, row0 = blockIdx.y * 64;
  int lane = tid & 63, w = tid >> 6;
  int wm = w >> 1, wn = w & 1;
  int lr = lane & 15, lk = (lane >> 4) * 8;

  int ar = tid >> 2, akq = (tid & 3) * 8;     // A: row 0..63, k-quad 0,8,16,24
  int bk = tid >> 3, bnq = (tid & 7) * 8;     // B: k 0..31, n-oct 0..56
  int rot = tid & 7;                          // B-write rotation

  f32x4 acc[2][2] = {};
  unsigned short a8[8], b8[8];

  // ---- prefetch tile k0 into registers ----
  auto load_tile = [&](int k0) {
    if (k0 < DIN) {
      if (BF16) {
        U8x16 t; t.v = *(const uint4*)((const unsigned short*)x + (size_t)(row0 + ar) * DIN + k0 + akq);
#pragma unroll
        for (int j = 0; j < 8; ++j) a8[j] = t.u[j];
      } else {
        const float4* q = (const float4*)((const float*)x + (size_t)(row0 + ar) * DIN + k0 + akq);
        float4 fa = q[0], fb = q[1];
        a8[0] = f2bu(fa.x); a8[1] = f2bu(fa.y); a8[2] = f2bu(fa.z); a8[3] = f2bu(fa.w);
        a8[4] = f2bu(fb.x); a8[5] = f2bu(fb.y); a8[6] = f2bu(fb.z); a8[7] = f2bu(fb.w);
      }
    } else {
      const float4* q = (const float4*)(ap + (size_t)(row0 + ar) * 128 + (k0 - DIN) + akq);
      float4 fa = q[0], fb = q[1];
      a8[0] = f2bu(fa.x); a8[1] = f2bu(fa.y); a8[2] = f2bu(fa.z); a8[3] = f2bu(fa.w);
      a8[4] = f2bu(fb.x); a8[5] = f2bu(fb.y); a8[6] = f2bu(fb.z); a8[7] = f2bu(fb.w);
    }
    if (BF16) {
      U8x16 t; t.v = *(const uint4*)((const unsigned short*)Wo + (size_t)(k0 + bk) * DOUT + col0 + bnq);
#pragma unroll
      for (int j = 0; j < 8; ++j) b8[j] = t.u[j];
    } else {
      const float4* q = (const float4*)((const float*)Wo + (size_t)(k0 + bk) * DOUT + col0 + bnq);
      float4 fa = q[0], fb = q[1];
      b8[0] = f2bu(fa.x); b8[1] = f2bu(fa.y); b8[2] = f2bu(fa.z); b8[3] = f2bu(fa.w);
      b8[4] = f2bu(fb.x); b8[5] = f2bu(fb.y); b8[6] = f2bu(fb.z); b8[7] = f2bu(fb.w);
    }
  };
  auto write_tile = [&](int buf) {
    U8x16 pk;
#pragma unroll
    for (int j = 0; j < 8; ++j) pk.u[j] = a8[j];
    *(uint4*)&As[buf][ar * ASTR + akq] = pk.v;
#pragma unroll
    for (int t = 0; t < 8; ++t) {
      int j = (t + rot) & 7;                    // rotated: 2-way (free) banks
      Bs[buf][(bnq + j) * ASTR + bk] = b8[j];
    }
  };

  load_tile(0);
  write_tile(0);

  for (int i = 0; i < NK; ++i) {
    __syncthreads();                            // tile i visible to all
    if (i + 1 < NK) load_tile((i + 1) * 32);    // overlap with MFMA below
    int cur = i & 1;
    short8 a0 = *(const short8*)&As[cur][(wm * 32 + lr) * ASTR + lk];
    short8 a1 = *(const short8*)&As[cur][(wm * 32 + 16 + lr) * ASTR + lk];
    short8 b0 = *(const short8*)&Bs[cur][(wn * 32 + lr) * ASTR + lk];
    short8 b1 = *(const short8*)&Bs[cur][(wn * 32 + 16 + lr) * ASTR + lk];
    acc[0][0] = __builtin_amdgcn_mfma_f32_16x16x32_bf16(a0, b0, acc[0][0], 0, 0, 0);
    acc[0][1] = __builtin_amdgcn_mfma_f32_16x16x32_bf16(a0, b1, acc[0][1], 0, 0, 0);
    acc[1][0] = __builtin_amdgcn_mfma_f32_16x16x32_bf16(a1, b0, acc[1][0], 0, 0, 0);
    acc[1][1] = __builtin_amdgcn_mfma_f32_16x16x32_bf16(a1, b1, acc[1][1], 0, 0, 0);
    if (i + 1 < NK) write_tile(cur ^ 1);        // other buffer: no race
  }

#pragma unroll
  for (int i = 0; i < 2; ++i) {
#pragma unroll
    for (int j2 = 0; j2 < 2; ++j2) {
      int c = col0 + wn * 32 + j2 * 16 + lr;
      float bias = ld<BF16>(bo, c);
#pragma unroll
      for (int r = 0; r < 4; ++r) {
        int rr = row0 + wm * 32 + i * 16 + (lane >> 4) * 4 + r;
        st<BF16>(dout, (size_t)rr * DOUT + c, acc[i][j2][r] + bias);
      }
    }
  }
}

// ---------------------------------------------------------------------------
extern "C" void kernel_launch(void* const* d_in, const int* in_sizes, int n_in,
                              void* d_out, int out_size, void* d_ws, size_t ws_size,
                              hipStream_t stream) {
  const void* x    = d_in[0];
  const void* mem  = d_in[1];
  const void* W_ar = d_in[2];
  const void* b_ar = d_in[3];
  const void* W_pr = d_in[4];
  const void* b_pr = d_in[5];
  const void* W_f  = d_in[6];
  const void* b_f  = d_in[7];
  const void* W_r  = d_in[8];
  const void* b_r  = d_in[9];
  const void* W_o  = d_in[10];
  const void* b_o  = d_in[11];

  int*            flag = (int*)d_ws;
  unsigned short* Wt   = (unsigned short*)((char*)d_ws + 16);        // 130*2048*2
  float*          px   = (float*)((char*)d_ws + 16 + PXW * DIN * 2); // 512*130 f32
  float*          ap   = px + NB * PXW;                              // 512*128 f32

  k_detect<<<1, 256, 0, stream>>>(x, flag);

  k_packW<false><<<DIN / 64, 256, 0, stream>>>(flag, W_ar, W_f, W_r, Wt);
  k_packW<true ><<<DIN / 64, 256, 0, stream>>>(flag, W_ar, W_f, W_r, Wt);

  k_proj_dot<false><<<NB, 256, 0, stream>>>(flag, x, Wt, b_ar, b_f, b_r, px);
  k_proj_dot<true ><<<NB, 256, 0, stream>>>(flag, x, Wt, b_ar, b_f, b_r, px);

  k_fused<false><<<NB, 256, 0, stream>>>(flag, mem, W_pr, b_pr, W_f, W_r, px, ap, d_out);
  k_fused<true ><<<NB, 256, 0, stream>>>(flag, mem, W_pr, b_pr, W_f, W_r, px, ap, d_out);

  dim3 g3(DOUT / 64, NB / 64);
  k_out_gemm<false><<<g3, 256, 0, stream>>>(flag, x, ap, W_o, b_o, d_out);
  k_out_gemm<true ><<<g3, 256, 0, stream>>>(flag, x, ap, W_o, b_o, d_out);
}

// Round 8
// 198.113 us; speedup vs baseline: 1.2286x; 1.2286x over previous
//
#include <hip/hip_runtime.h>
#include <hip/hip_bf16.h>

// Problem: B=512, N_SLOTS=128, IN=2048, MEM=64, OUT=2048.
// Dtype self-detection: each wave ballots on x's bit patterns (fp32 buffers
// holding bf16-quantized values, per R4-R7 evidence; bf16 world also handled).
// Pipeline (4 dispatches): k_pack (bf16-pack A/x, Wo^T, proj weights, biases)
// -> k_proj_dot (px) -> k_fused (scores/softmax/recalls/mem-update, writes
// active|passive into A's tail) -> k_gemm (barrier-free wave-tiled MFMA).
// d_out = [output (512*2048) | new_memory (512*128*64)], input dtype.

#define NB    512
#define NSLOT 128
#define DIN   2048
#define DMEM  64
#define DOUT  2048
#define PXW   130              // 64 (q) + 1 (forget) + 65 (remember)
#define KT    (DIN + 2 * DMEM) // 2176 = GEMM K and packed row stride
#define NK    (KT / 32)        // 68

typedef __hip_bfloat16 bf16;
typedef __attribute__((ext_vector_type(8))) short short8;
typedef __attribute__((ext_vector_type(4))) float f32x4;

template<bool BF16>
__device__ __forceinline__ float ld(const void* p, size_t i) {
  if (BF16) return __bfloat162float(((const bf16*)p)[i]);
  return ((const float*)p)[i];
}
template<bool BF16>
__device__ __forceinline__ void st(void* p, size_t i, float v) {
  if (BF16) ((bf16*)p)[i] = __float2bfloat16(v);
  else      ((float*)p)[i] = v;
}
// f32 -> bf16 bits (RNE); bf16 bits -> f32 (exact).
__device__ __forceinline__ unsigned short f2bu(float f) {
  unsigned int u = __builtin_bit_cast(unsigned int, f);
  u = (u + 0x7FFFu + ((u >> 16) & 1u)) >> 16;
  return (unsigned short)u;
}
__device__ __forceinline__ float bu2f(unsigned short u) {
  unsigned int w = ((unsigned int)u) << 16;
  return __builtin_bit_cast(float, w);
}

// Wave-level dtype detect: sample 64 even uint16 positions of x. bf16 data ->
// sane exponents (~100% of N(0,1)); f32 data -> even positions are mantissa
// low-halves (~16% sane). All waves sample identical addresses -> identical
// verdict everywhere, every launch (x is pristine-restored).
__device__ __forceinline__ bool detect_bf16(const void* x) {
  const unsigned short* u = (const unsigned short*)x;
  int lane = threadIdx.x & 63;
  unsigned short v = u[lane * 2048];
  int e = (v >> 7) & 0xFF;
  unsigned long long m = __ballot(e >= 100 && e <= 140);
  return __popcll(m) > 32;
}

union U8x16 { uint4 v; unsigned short u[8]; };

// ---------------------------------------------------------------------------
// k_pack: one dispatch, block ranges:
//  [0,1088)   : Bt[n][k] = Wo[k][n] bf16   (34 k-tiles x 32 n-tiles, LDS transpose)
//  [1088,1216): Abf[b][0:2048] = x bf16    (4 rows/block)
//  [1216,1280): Wt[j][k] = proj-weight col j (LDS transpose, 65-col halves)
//  [1280,1288): bias_o[2048] f32
//  [1288]     : bias_px[130] f32
// ---------------------------------------------------------------------------
template<bool BF16>
__device__ void pack_body(
    const void* x, const void* W_ar, const void* W_f, const void* W_r,
    const void* Wo, const void* b_ar, const void* b_f, const void* b_r,
    const void* bo,
    unsigned short* Abf, unsigned short* Bt, unsigned short* Wt,
    float* bias_o, float* bias_px, unsigned short* tile) {
  int t = blockIdx.x, tid = threadIdx.x;
  if (t < 1088) {
    int kt = t % 34, nt = t / 34;
    int k0 = kt * 64, n0 = nt * 64;
    for (int i = tid; i < 64 * 64; i += 256) {
      int kk = i >> 6, nn = i & 63;   // consecutive tid -> consecutive nn (coalesced)
      tile[nn * 66 + kk] = f2bu(ld<BF16>(Wo, (size_t)(k0 + kk) * DOUT + n0 + nn));
    }
    __syncthreads();
    for (int i = tid; i < 64 * 64; i += 256) {
      int nn = i >> 6, kk = i & 63;   // consecutive kk -> coalesced 128B writes
      Bt[(size_t)(n0 + nn) * KT + k0 + kk] = tile[nn * 66 + kk];
    }
  } else if (t < 1216) {
    int bx = t - 1088;
    for (int i = tid; i < 8192; i += 256) {
      int r = bx * 4 + (i >> 11), c = i & 2047;
      Abf[(size_t)r * KT + c] = f2bu(ld<BF16>(x, (size_t)r * DIN + c));
    }
  } else if (t < 1280) {
    int q = t - 1216;
    int k0 = (q >> 1) * 64, j0 = (q & 1) * 65;
    for (int i = tid; i < 64 * 65; i += 256) {
      int kl = i / 65, jl = i % 65;   // consecutive tid -> consecutive jl
      int j = j0 + jl, k = k0 + kl;
      float v;
      if (j < 64)       v = ld<BF16>(W_ar, (size_t)k * 64 + j);
      else if (j == 64) v = ld<BF16>(W_f, k);
      else              v = ld<BF16>(W_r, (size_t)k * 65 + (j - 65));
      tile[jl * 66 + kl] = f2bu(v);
    }
    __syncthreads();
    for (int i = tid; i < 65 * 64; i += 256) {
      int jl = i >> 6, kk = i & 63;
      Wt[(size_t)(j0 + jl) * DIN + k0 + kk] = tile[jl * 66 + kk];
    }
  } else if (t < 1288) {
    int c = (t - 1280) * 256 + tid;
    bias_o[c] = ld<BF16>(bo, c);
  } else {
    if (tid < PXW) {
      float v;
      if (tid < 64)       v = ld<BF16>(b_ar, tid);
      else if (tid == 64) v = ld<BF16>(b_f, 0);
      else                v = ld<BF16>(b_r, tid - 65);
      bias_px[tid] = v;
    }
  }
}

__global__ __launch_bounds__(256) void k_pack(
    const void* __restrict__ x, const void* __restrict__ W_ar,
    const void* __restrict__ W_f, const void* __restrict__ W_r,
    const void* __restrict__ Wo, const void* __restrict__ b_ar,
    const void* __restrict__ b_f, const void* __restrict__ b_r,
    const void* __restrict__ bo,
    unsigned short* __restrict__ Abf, unsigned short* __restrict__ Bt,
    unsigned short* __restrict__ Wt, float* __restrict__ bias_o,
    float* __restrict__ bias_px) {
  __shared__ unsigned short tile[65 * 66];
  if (detect_bf16(x))
    pack_body<true >(x, W_ar, W_f, W_r, Wo, b_ar, b_f, b_r, bo, Abf, Bt, Wt, bias_o, bias_px, tile);
  else
    pack_body<false>(x, W_ar, W_f, W_r, Wo, b_ar, b_f, b_r, bo, Abf, Bt, Wt, bias_o, bias_px, tile);
}

// ---------------------------------------------------------------------------
// k_proj_dot: px[b][j] = dot(x[b], Wt[j]) + bias_px[j].  Dtype-free (bf16 ws).
// ---------------------------------------------------------------------------
__global__ __launch_bounds__(256) void k_proj_dot(
    const unsigned short* __restrict__ Abf,
    const unsigned short* __restrict__ Wt,
    const float* __restrict__ bias_px,
    float* __restrict__ px) {
  __shared__ float xs[DIN];
  int b = blockIdx.x;
  for (int k = threadIdx.x; k < DIN; k += 256) xs[k] = bu2f(Abf[(size_t)b * KT + k]);
  __syncthreads();
  int wv = threadIdx.x >> 6, lane = threadIdx.x & 63;
  for (int j = wv; j < PXW; j += 4) {
    const unsigned short* wc = Wt + (size_t)j * DIN;
    float acc = 0.f;
#pragma unroll
    for (int i = 0; i < 4; ++i) {
      int k0 = i * 512 + lane * 8;
      U8x16 t; t.v = *(const uint4*)(wc + k0);
      const float4* xp = (const float4*)&xs[k0];
      float4 xa = xp[0], xb = xp[1];
      acc += xa.x * bu2f(t.u[0]) + xa.y * bu2f(t.u[1])
           + xa.z * bu2f(t.u[2]) + xa.w * bu2f(t.u[3])
           + xb.x * bu2f(t.u[4]) + xb.y * bu2f(t.u[5])
           + xb.z * bu2f(t.u[6]) + xb.w * bu2f(t.u[7]);
    }
#pragma unroll
    for (int off = 32; off; off >>= 1) acc += __shfl_xor(acc, off, 64);
    if (lane == 0) px[b * PXW + j] = acc + bias_px[j];
  }
}

// ---------------------------------------------------------------------------
// k_fused: per-batch — per-slot dots, two LDS-tree softmaxes, recalls (into
// Abf tail, bf16), gated memory update (into d_out, input dtype).
// ---------------------------------------------------------------------------
template<bool BF16>
__device__ void fused_body(
    const void* memory, const void* W_pr, const void* b_pr,
    const void* W_f, const void* W_r, const float* px,
    unsigned short* Abf, void* dout,
    float* mem_s, float* wrm_s, float* smem) {
  float* wfm_s = smem;            // 64
  float* wpr_s = wfm_s + 64;      // 64
  float* qs    = wpr_s + 64;      // 64
  float* pxr_s = qs + 64;         // 65
  float* sa    = pxr_s + 65;      // 128
  float* sp    = sa + 128;        // 128
  float* ra    = sp + 128;        // 128
  float* rb    = ra + 128;        // 128
  float* forget_s = rb + 128;     // 128
  float* r64_s    = forget_s + 128;

  int b = blockIdx.x, tid = threadIdx.x;
  size_t mb = (size_t)b * (NSLOT * DMEM);
  for (int i = tid; i < NSLOT * DMEM; i += 256)
    mem_s[(i >> 6) * 65 + (i & 63)] = ld<BF16>(memory, mb + i);
  for (int i = tid; i < 64 * 65; i += 256)
    wrm_s[(i / 65) * 68 + (i % 65)] = ld<BF16>(W_r, 2048 * 65 + i);
  if (tid < 64) {
    wfm_s[tid] = ld<BF16>(W_f, 2048 + tid);
    wpr_s[tid] = ld<BF16>(W_pr, tid);
    qs[tid]    = px[b * PXW + tid];
  }
  if (tid < 65) pxr_s[tid] = px[b * PXW + 65 + tid];
  __syncthreads();

  float pxf = px[b * PXW + 64];

  if (tid < 128) {
    const float* mr = &mem_s[tid * 65];
    float aa = 0.f, pp = 0.f, ff = 0.f, rr = 0.f;
#pragma unroll 8
    for (int k = 0; k < 64; ++k) {
      float m = mr[k];
      aa += m * qs[k];
      pp += m * wpr_s[k];
      ff += m * wfm_s[k];
      rr += m * wrm_s[k * 68 + 64];
    }
    sa[tid] = aa;
    sp[tid] = pp + ld<BF16>(b_pr, 0);
    forget_s[tid] = 1.1f / (1.f + __expf(-(ff + pxf)));
    r64_s[tid]    = rr + pxr_s[64];
  }
  __syncthreads();

  if (tid < 128) ra[tid] = sa[tid]; else rb[tid - 128] = sp[tid - 128];
  __syncthreads();
  for (int s = 64; s; s >>= 1) {
    if (tid < s) ra[tid] = fmaxf(ra[tid], ra[tid + s]);
    else if (tid >= 128 && tid < 128 + s) rb[tid - 128] = fmaxf(rb[tid - 128], rb[tid - 128 + s]);
    __syncthreads();
  }
  float mxA = ra[0], mxB = rb[0];
  __syncthreads();
  if (tid < 128) { float e = __expf(sa[tid] - mxA); sa[tid] = e; ra[tid] = e; }
  else           { float e = __expf(sp[tid - 128] - mxB); sp[tid - 128] = e; rb[tid - 128] = e; }
  __syncthreads();
  for (int s = 64; s; s >>= 1) {
    if (tid < s) ra[tid] += ra[tid + s];
    else if (tid >= 128 && tid < 128 + s) rb[tid - 128] += rb[tid - 128 + s];
    __syncthreads();
  }
  float invA = 1.f / ra[0], invB = 1.f / rb[0];
  __syncthreads();
  if (tid < 128) sa[tid] *= invA; else sp[tid - 128] *= invB;
  __syncthreads();

  // recalls -> Abf[b][2048 + 0:128] as bf16 (GEMM A tail)
  if (tid < 128) {
    int m = tid & 63;
    const float* w = (tid < 64) ? sa : sp;
    float acc = 0.f;
#pragma unroll 8
    for (int n = 0; n < NSLOT; ++n) acc += mem_s[n * 65 + m] * w[n];
    Abf[(size_t)b * KT + DIN + tid] = f2bu(acc);
  }

  size_t obase = (size_t)NB * DOUT + mb;
  for (int Q = tid; Q < NSLOT * 16; Q += 256) {
    int n = Q >> 4, j0 = (Q & 15) * 4;
    const float* mr = &mem_s[n * 65];
    float r0 = 0.f, r1 = 0.f, r2 = 0.f, r3 = 0.f;
#pragma unroll 8
    for (int k = 0; k < 64; ++k) {
      float mv = mr[k];
      const float* wr = &wrm_s[k * 68 + j0];
      r0 += mv * wr[0]; r1 += mv * wr[1]; r2 += mv * wr[2]; r3 += mv * wr[3];
    }
    float fg = forget_s[n], r64 = r64_s[n];
    size_t o = obase + n * DMEM + j0;
    st<BF16>(dout, o + 0, mr[j0 + 0] * fg + r64 * (r0 + pxr_s[j0 + 0]));
    st<BF16>(dout, o + 1, mr[j0 + 1] * fg + r64 * (r1 + pxr_s[j0 + 1]));
    st<BF16>(dout, o + 2, mr[j0 + 2] * fg + r64 * (r2 + pxr_s[j0 + 2]));
    st<BF16>(dout, o + 3, mr[j0 + 3] * fg + r64 * (r3 + pxr_s[j0 + 3]));
  }
}

__global__ __launch_bounds__(256) void k_fused(
    const void* __restrict__ x, const void* __restrict__ memory,
    const void* __restrict__ W_pr, const void* __restrict__ b_pr,
    const void* __restrict__ W_f,  const void* __restrict__ W_r,
    const float* __restrict__ px,
    unsigned short* __restrict__ Abf, void* __restrict__ dout) {
  __shared__ float mem_s[NSLOT * 65];
  __shared__ float wrm_s[64 * 68];
  __shared__ float smem[64 * 4 + 65 + 128 * 6];
  if (detect_bf16(x))
    fused_body<true >(memory, W_pr, b_pr, W_f, W_r, px, Abf, dout, mem_s, wrm_s, smem);
  else
    fused_body<false>(memory, W_pr, b_pr, W_f, W_r, px, Abf, dout, mem_s, wrm_s, smem);
}

// ---------------------------------------------------------------------------
// k_gemm: output = Abf @ Bt^T + bias_o, barrier-free wave tiling.
// 256 blocks x 4 waves; wave tile 16 rows x 64 cols; fragments loaded
// global->register (16B/lane), one-tile register prefetch, no LDS.
// Fragment layouts (m89/m91 + verified in R5-R7): A/B: m|n=lane&15,
// k=(lane>>4)*8+j ; D: col=lane&15, row=(lane>>4)*4+reg.
// ---------------------------------------------------------------------------
template<bool BF16>
__device__ void gemm_body(const unsigned short* Abf, const unsigned short* Bt,
                          const float* bias_o, void* dout) {
  int tid = threadIdx.x;
  int lane = tid & 63, w = tid >> 6;
  int bc = blockIdx.x & 31, br = blockIdx.x >> 5;
  int col0 = bc * 64, row0 = br * 64 + w * 16;
  int lr = lane & 15, lk = (lane >> 4) * 8;

  const unsigned short* Ap = Abf + (size_t)(row0 + lr) * KT + lk;
  const unsigned short* Bp = Bt  + (size_t)(col0 + lr) * KT + lk;

  f32x4 acc0 = {}, acc1 = {}, acc2 = {}, acc3 = {};
  short8 ac  = *(const short8*)Ap;
  short8 bc0 = *(const short8*)(Bp);
  short8 bc1 = *(const short8*)(Bp + 16 * KT);
  short8 bc2 = *(const short8*)(Bp + 32 * KT);
  short8 bc3 = *(const short8*)(Bp + 48 * KT);

  for (int i = 0; i < NK; ++i) {
    short8 an = {}, bn0 = {}, bn1 = {}, bn2 = {}, bn3 = {};
    if (i + 1 < NK) {
      int k = (i + 1) * 32;
      an  = *(const short8*)(Ap + k);
      bn0 = *(const short8*)(Bp + k);
      bn1 = *(const short8*)(Bp + 16 * KT + k);
      bn2 = *(const short8*)(Bp + 32 * KT + k);
      bn3 = *(const short8*)(Bp + 48 * KT + k);
    }
    acc0 = __builtin_amdgcn_mfma_f32_16x16x32_bf16(ac, bc0, acc0, 0, 0, 0);
    acc1 = __builtin_amdgcn_mfma_f32_16x16x32_bf16(ac, bc1, acc1, 0, 0, 0);
    acc2 = __builtin_amdgcn_mfma_f32_16x16x32_bf16(ac, bc2, acc2, 0, 0, 0);
    acc3 = __builtin_amdgcn_mfma_f32_16x16x32_bf16(ac, bc3, acc3, 0, 0, 0);
    ac = an; bc0 = bn0; bc1 = bn1; bc2 = bn2; bc3 = bn3;
  }

  int rbase = row0 + (lane >> 4) * 4;
  f32x4 accs[4] = {acc0, acc1, acc2, acc3};
#pragma unroll
  for (int j = 0; j < 4; ++j) {
    int c = col0 + j * 16 + lr;
    float bias = bias_o[c];
#pragma unroll
    for (int r = 0; r < 4; ++r)
      st<BF16>(dout, (size_t)(rbase + r) * DOUT + c, accs[j][r] + bias);
  }
}

__global__ __launch_bounds__(256) void k_gemm(
    const void* __restrict__ x,
    const unsigned short* __restrict__ Abf,
    const unsigned short* __restrict__ Bt,
    const float* __restrict__ bias_o, void* __restrict__ dout) {
  if (detect_bf16(x)) gemm_body<true >(Abf, Bt, bias_o, dout);
  else                gemm_body<false>(Abf, Bt, bias_o, dout);
}

// ---------------------------------------------------------------------------
extern "C" void kernel_launch(void* const* d_in, const int* in_sizes, int n_in,
                              void* d_out, int out_size, void* d_ws, size_t ws_size,
                              hipStream_t stream) {
  const void* x    = d_in[0];
  const void* mem  = d_in[1];
  const void* W_ar = d_in[2];
  const void* b_ar = d_in[3];
  const void* W_pr = d_in[4];
  const void* b_pr = d_in[5];
  const void* W_f  = d_in[6];
  const void* b_f  = d_in[7];
  const void* W_r  = d_in[8];
  const void* b_r  = d_in[9];
  const void* W_o  = d_in[10];
  const void* b_o  = d_in[11];

  unsigned short* Abf    = (unsigned short*)d_ws;          // 512*2176
  unsigned short* Bt     = Abf + (size_t)NB * KT;          // 2048*2176
  unsigned short* Wt     = Bt + (size_t)DOUT * KT;         // 130*2048
  float*          bias_o = (float*)(Wt + PXW * DIN);       // 2048
  float*          bias_px= bias_o + DOUT;                  // 130 (+pad)
  float*          px     = bias_px + 132;                  // 512*130

  k_pack<<<1289, 256, 0, stream>>>(x, W_ar, W_f, W_r, W_o, b_ar, b_f, b_r, b_o,
                                   Abf, Bt, Wt, bias_o, bias_px);
  k_proj_dot<<<NB, 256, 0, stream>>>(Abf, Wt, bias_px, px);
  k_fused<<<NB, 256, 0, stream>>>(x, mem, W_pr, b_pr, W_f, W_r, px, Abf, d_out);
  k_gemm<<<256, 256, 0, stream>>>(x, Abf, Bt, bias_o, d_out);
}